// Round 15
// baseline (2477.340 us; speedup 1.0000x reference)
//
#include <hip/hip_runtime.h>

#define EE 256
#define GG 32000
#define NSTEP 128
#define ROWS 4096
#define VSPLIT 4
#define NWGP 32
#define NWGD 64
#define NWGR (NWGP + NWGD)

typedef __attribute__((ext_vector_type(8))) short bf16x8;
typedef __attribute__((ext_vector_type(4))) float f32x4;
typedef __attribute__((ext_vector_type(2))) unsigned long long u64x2;

// ---------- workspace layout (bytes) ----------
#define OFF_ZSB  0u                      // bf16 zs 4096x256 = 2 MB
#define OFF_PS   2097152u                // f32 4x4096 = 64 KB
#define OFF_PT   (OFF_PS + 65536u)       // 64 KB
#define OFF_ZNB  (OFF_PT + 65536u)       // u32 2 planes x 32 x 128 = 32 KB
#define OFF_BAR  (OFF_ZNB + 32768u)      // 4 KB ints
#define OFF_PD   (OFF_BAR + 4096u)       // f32 32 b x 256 e x 16 g = 512 KB
#define WS_REQ   (OFF_PD + 524288u)      // 2,789,376 B (< confirmed 4,460,544)
#define OFF_VB   WS_REQ                  // optional bf16 vocab 16,384,000 B
#define VB_BYTES 16384000u

// bar int slots: flagsA[0..31] (P1 arrive), flagsB[64..127] (D arrive),
// dead@132, mfmachk@133, is64@136

__device__ __forceinline__ float wredf(float v){
    #pragma unroll
    for (int m = 1; m < 64; m <<= 1) v += __shfl_xor(v, m);
    return v;
}
__device__ __forceinline__ unsigned short f2bf_bits(float f){
    unsigned int u = __float_as_uint(f);
    unsigned int lsb = (u >> 16) & 1u;
    u += 0x7fffu + lsb;
    return (unsigned short)(u >> 16);
}
__device__ __forceinline__ float bf2f(unsigned short u){
    return __uint_as_float(((unsigned int)u) << 16);
}
__device__ __forceinline__ float aload(const float* p){
    return __hip_atomic_load(p, __ATOMIC_RELAXED, __HIP_MEMORY_SCOPE_AGENT);
}
__device__ __forceinline__ void astore(float* p, float v){
    __hip_atomic_store(p, v, __ATOMIC_RELAXED, __HIP_MEMORY_SCOPE_AGENT);
}
__device__ __forceinline__ void astoreu(unsigned* p, unsigned v){
    __hip_atomic_store(p, v, __ATOMIC_RELAXED, __HIP_MEMORY_SCOPE_AGENT);
}
__device__ __forceinline__ unsigned long long aload64(const unsigned long long* p){
    return __hip_atomic_load(p, __ATOMIC_RELAXED, __HIP_MEMORY_SCOPE_AGENT);
}
// poll one flag until >= gen (with timeout -> dead)
__device__ __forceinline__ void pollflag(int* bar, int idx, int gen){
    int spins = 0;
    while (__hip_atomic_load(&bar[idx], __ATOMIC_RELAXED, __HIP_MEMORY_SCOPE_AGENT) < gen){
        __builtin_amdgcn_s_sleep(1);
        if (++spins > 2000000){
            __hip_atomic_store(&bar[132], 1, __ATOMIC_RELAXED, __HIP_MEMORY_SCOPE_AGENT);
            break;
        }
        if ((spins & 2047) == 0 &&
            __hip_atomic_load(&bar[132], __ATOMIC_RELAXED, __HIP_MEMORY_SCOPE_AGENT) != 0)
            break;
    }
}

__global__ __launch_bounds__(256) void k_sentinel(float* __restrict__ outp, float val){
    int r = blockIdx.x * 256 + threadIdx.x;
    outp[r] = val;
}

__global__ void k_prep(const int* __restrict__ zi, int* __restrict__ bar){
    int t = threadIdx.x;
    bar[t] = 0;            // re-zeroed EVERY replay
    __syncthreads();
    if (t == 0){
        bool odd_zero = true, even_ok = true;
        for (int i = 0; i < 16; ++i){
            int lo = zi[2*i], hi = zi[2*i+1];
            if (hi != 0) odd_zero = false;
            if (lo < 0 || lo >= 8192) even_ok = false;
        }
        bar[136] = (odd_zero && even_ok) ? 1 : 0;
    }
}

// ---------------- vocab f32 -> bf16 (RNE, matches pack8f) ----------------
__global__ __launch_bounds__(256) void k_cvt(const float* __restrict__ in,
                                             unsigned short* __restrict__ outp)
{
    int i = (blockIdx.x * 256 + threadIdx.x) * 4;
    float4 v = *(const float4*)&in[i];
    ushort4 o;
    o.x = f2bf_bits(v.x); o.y = f2bf_bits(v.y);
    o.z = f2bf_bits(v.z); o.w = f2bf_bits(v.w);
    *(ushort4*)&outp[i] = o;
}

// ---------------- fused recurrence: 96 WGs, producer-consumer pipeline -------
// WGs 0..31  (P1, one per batch): gather a2-weighted PD -> z -> zn -> publish
//   ZNB -> flagA ; then OVERLAPPED tail: logits/softmax (a2 stays local)/emit.
// WGs 32..95 (D): W hi/lo A-fragments in REGISTERS; per step: wait flagsA ->
//   build B-fragments directly from LLC (u64 atomic loads) -> MFMA -> publish
//   raw U into PD[b][e][g] -> flagB.
__global__ __launch_bounds__(512, 1) void k_rnn(const float* __restrict__ latent,
                                                const int* __restrict__ zi,
                                                const float* __restrict__ anchor_w,
                                                const float* __restrict__ anchor_b,
                                                const float* __restrict__ trans_w,
                                                const float* __restrict__ trans_b,
                                                unsigned short* __restrict__ zsb,
                                                unsigned* __restrict__ ZNB,
                                                float* __restrict__ PD,
                                                int* __restrict__ bar)
{
    __shared__ float xk_l[16][260];      // (P1)
    __shared__ float xv_l[16][260];      // (P1)
    __shared__ float zl[256];
    __shared__ float a2s[16];
    __shared__ float tbl[2][32];         // (D)
    __shared__ float l1s[16], l2s[16], ab_l[16], rbuf[8];

    const int wg = blockIdx.x, t = threadIdx.x;
    const int is64 = bar[136];
    const int lane = t & 63, wv = t >> 6;
    const int kg = lane >> 4, nl = lane & 15;

    if (wg < NWGP){
        // ======================= P1 role (batch b) =======================
        const int b = wg;
        int zb = is64 ? zi[2*b] : zi[b];
        const float* base = latent + (size_t)zb * 8192;  // xk=base[0:4096]*100, xv=base[4096:]*100
        for (int i = t; i < 4096; i += 512){
            int s = i >> 8, c = i & 255;
            xk_l[s][c] = base[i];
            xv_l[s][c] = base[4096 + i];
        }
        if (t < 16) ab_l[t] = anchor_b[t];
        __syncthreads();

        float zn_r = 0.f, em_r = 0.f;
        for (int stp = 0; stp < NSTEP; ++stp){
            if (stp > 0){
                if (t < NWGD) pollflag(bar, 64 + t, stp);   // wait all D done
                __syncthreads();
                __builtin_amdgcn_sched_barrier(0);
            }
            // ---- head: z update + norm + publish zn ----
            float zv = 0.f;
            if (t < 256){
                if (stp == 0) zv = base[t];
                else {
                    // PD[b][e=t][g=0..15] contiguous -> 8 x u64 loads
                    const unsigned long long* PD64 = (const unsigned long long*)PD;
                    const int b64 = (b*4096 + t*16) >> 1;
                    float dz = 0.f;
                    #pragma unroll
                    for (int h = 0; h < 8; ++h){
                        unsigned long long v = aload64(&PD64[b64 + h]);
                        float2 f = __builtin_bit_cast(float2, v);
                        dz += a2s[2*h] * f.x + a2s[2*h+1] * f.y;
                    }
                    zv = zn_r + em_r + dz;
                }
                float s1 = wredf(zv), s2 = wredf(zv*zv);
                if ((t & 63) == 0){ rbuf[t>>6] = s1; rbuf[4 + (t>>6)] = s2; }
            }
            __syncthreads();
            if (t < 256){
                float tot1 = rbuf[0]+rbuf[1]+rbuf[2]+rbuf[3];
                float tot2 = rbuf[4]+rbuf[5]+rbuf[6]+rbuf[7];
                float mean = tot1 * (1.0f/EE);
                float var  = (tot2 - (float)EE*mean*mean) * (1.0f/(EE-1));
                var = fmaxf(var, 0.f);
                float sc = 0.113f / (1e-5f + sqrtf(var));
                zn_r = zv * sc;
                zl[t] = zn_r;
                if (stp < NSTEP-1){
                    unsigned short zh  = f2bf_bits(zn_r);
                    unsigned short zlo = f2bf_bits(zn_r - bf2f(zh));
                    unsigned ohi = (unsigned)__shfl_xor((int)(unsigned)zh, 1);
                    unsigned olo = (unsigned)__shfl_xor((int)(unsigned)zlo, 1);
                    if (!(t & 1)){
                        astoreu(&ZNB[b*128 + (t >> 1)],        (unsigned)zh  | (ohi << 16));
                        astoreu(&ZNB[4096 + b*128 + (t >> 1)], (unsigned)zlo | (olo << 16));
                    }
                }
            }
            __syncthreads();                     // drains ZNB stores (vmcnt)
            if (stp < NSTEP-1 && t == 0)
                __hip_atomic_store(&bar[b], stp + 1, __ATOMIC_RELAXED, __HIP_MEMORY_SCOPE_AGENT);

            // ---- tail (overlaps with D phase): logits/softmax/emit ----
            if (t < 256){
                int sidx = t >> 4, L = t & 15;
                const float* aws = anchor_w + sidx*EE;
                float p1 = 0.f, p2 = 0.f;
                #pragma unroll
                for (int c = 0; c < 16; ++c){
                    int k = L*16 + c;
                    float z = zl[k];
                    p1 += z * xk_l[sidx][k];
                    p2 += z * aws[k];
                }
                #pragma unroll
                for (int mm = 1; mm < 16; mm <<= 1){ p1 += __shfl_xor(p1, mm); p2 += __shfl_xor(p2, mm); }
                if (L == 0){ l1s[sidx] = p1 * 100.0f; l2s[sidx] = p2 + ab_l[sidx]; }
            }
            __syncthreads();
            if (t < 256){
                float mx1 = -1e30f, mx2 = -1e30f;
                #pragma unroll
                for (int s = 0; s < 16; ++s){ mx1 = fmaxf(mx1, l1s[s]); mx2 = fmaxf(mx2, l2s[s]); }
                float att[16]; float sum1 = 0.f, sum2 = 0.f;
                #pragma unroll
                for (int s = 0; s < 16; ++s){
                    att[s] = expf(l1s[s] - mx1); sum1 += att[s];
                    sum2  += expf(l2s[s] - mx2);
                }
                float inv1 = 1.0f / sum1;
                if (t < 16) a2s[t] = expf(l2s[t] - mx2) / sum2;   // stays local!
                float em = 0.f;
                #pragma unroll
                for (int s = 0; s < 16; ++s) em += (att[s] * inv1) * xv_l[s][t];
                em *= 100.0f;
                em_r = em;
                zsb[((size_t)b*NSTEP + stp)*EE + t] = f2bf_bits(em);
            }
            __syncthreads();                     // a2s ready for next gather
        }
    } else {
        // ======================= D role =======================
        const int d = wg - NWGP;
        const int mh = d >> 3, q = d & 7;
        const int m = wv >> 2, et = (wv >> 1) & 1, bt = wv & 1;
        const int brow = bt*16 + nl;

        // A-fragments (W hi/lo) in registers for ALL steps.
        // A[row = et*16+nl within (m,q) slice][k = kk*32 + kg*8 + j]
        bf16x8 Ah[8], Al[8];
        {
            const int grow = (2*mh + m)*256 + q*32 + et*16 + nl;
            const float* wp = trans_w + (size_t)grow * 256;
            #pragma unroll
            for (int kk = 0; kk < 8; ++kk){
                float4 w0 = *(const float4*)&wp[kk*32 + kg*8];
                float4 w1 = *(const float4*)&wp[kk*32 + kg*8 + 4];
                float ws[8] = {w0.x,w0.y,w0.z,w0.w,w1.x,w1.y,w1.z,w1.w};
                bf16x8 ah, al;
                #pragma unroll
                for (int j = 0; j < 8; ++j){
                    unsigned short hh = f2bf_bits(ws[j]);
                    ah[j] = (short)hh;
                    al[j] = (short)f2bf_bits(ws[j] - bf2f(hh));
                }
                Ah[kk] = ah; Al[kk] = al;
            }
        }
        if (t < 64) tbl[t >> 5][t & 31] = trans_b[(2*mh + (t >> 5))*256 + q*32 + (t & 31)];
        __syncthreads();

        const unsigned long long* Z64 = (const unsigned long long*)ZNB;
        for (int k = 1; k < NSTEP; ++k){
            if (t < NWGP) pollflag(bar, t, k);      // wait all P1 published ZNB(k-1)
            __syncthreads();
            __builtin_amdgcn_sched_barrier(0);

            // B-fragments direct from LLC: B[col=brow][k = kk*32 + kg*8 + j]
            f32x4 acc = {0.f, 0.f, 0.f, 0.f};
            #pragma unroll
            for (int kk = 0; kk < 8; ++kk){
                const int bi = brow*64 + kk*8 + kg*2;
                u64x2 th, tl;
                th.x = aload64(&Z64[bi]);
                th.y = aload64(&Z64[bi + 1]);
                tl.x = aload64(&Z64[2048 + bi]);
                tl.y = aload64(&Z64[2048 + bi + 1]);
                bf16x8 bh = __builtin_bit_cast(bf16x8, th);
                bf16x8 bl = __builtin_bit_cast(bf16x8, tl);
                acc = __builtin_amdgcn_mfma_f32_16x16x32_bf16(Ah[kk], bh, acc, 0, 0, 0);
                acc = __builtin_amdgcn_mfma_f32_16x16x32_bf16(Ah[kk], bl, acc, 0, 0, 0);
                acc = __builtin_amdgcn_mfma_f32_16x16x32_bf16(Al[kk], bh, acc, 0, 0, 0);
            }
            #pragma unroll
            for (int i = 0; i < 4; ++i){
                int e_loc = et*16 + kg*4 + i;        // C/D: row=kg*4+i (e), col=nl (b)
                float u = acc[i] + tbl[m][e_loc];
                astore(&PD[brow*4096 + (q*32 + e_loc)*16 + 2*mh + m], u);
            }
            __syncthreads();                          // drains PD stores
            if (t == 0)
                __hip_atomic_store(&bar[64 + d], k, __ATOMIC_RELAXED, __HIP_MEMORY_SCOPE_AGENT);
        }
    }
}

// ---------------- vocab: bf16 MFMA logits + streaming sumexp + target ----------
__device__ __forceinline__ bf16x8 pack8f(const float* __restrict__ src){
    bf16x8 r;
    #pragma unroll
    for (int j = 0; j < 8; ++j) r[j] = (short)f2bf_bits(src[j]);
    return r;
}

template<bool VB>
__global__ __launch_bounds__(256, 1) void k_vocab(const unsigned short* __restrict__ vb,
                                                  const float* __restrict__ vwf,
                                                  const float* __restrict__ vbias,
                                                  const unsigned short* __restrict__ zsb,
                                                  const int* __restrict__ y,
                                                  float* __restrict__ pS,
                                                  float* __restrict__ pT,
                                                  int* __restrict__ bar)
{
    const int rowblk = blockIdx.x;
    const int split  = blockIdx.y;
    const int t = threadIdx.x;
    const int wave = t >> 6, lane = t & 63;
    const int kg = lane >> 4, nl = lane & 15;
    const int is64 = bar[136];

    __shared__ float psum_l[4][64];
    __shared__ float ptarg_l[4][64];
    __shared__ float chk[1];

    bf16x8 afr[4][8];
    #pragma unroll
    for (int mt = 0; mt < 4; ++mt)
        #pragma unroll
        for (int kk = 0; kk < 8; ++kk)
            afr[mt][kk] = *(const bf16x8*)&zsb[(size_t)(rowblk*64 + mt*16 + nl) * EE + kk*32 + kg*8];

    int tg[4][4];
    #pragma unroll
    for (int mt = 0; mt < 4; ++mt)
        #pragma unroll
        for (int i = 0; i < 4; ++i){
            int rg = rowblk*64 + mt*16 + kg*4 + i;
            tg[mt][i] = is64 ? y[2*rg] : y[rg];
        }

    float sums[4][4]; float targ[4][4];
    #pragma unroll
    for (int mt = 0; mt < 4; ++mt)
        #pragma unroll
        for (int i = 0; i < 4; ++i){ sums[mt][i] = 0.f; targ[mt][i] = 0.f; }

    for (int tile = wave; tile < 500; tile += 4){
        int n = split*8000 + tile*16 + nl;
        f32x4 acc[4];
        #pragma unroll
        for (int mt = 0; mt < 4; ++mt) acc[mt] = (f32x4){0.f,0.f,0.f,0.f};
        #pragma unroll
        for (int kk = 0; kk < 8; ++kk){
            bf16x8 bfr;
            if (VB) bfr = *(const bf16x8*)&vb[(size_t)n * EE + kk*32 + kg*8];
            else    bfr = pack8f(&vwf[(size_t)n * EE + kk*32 + kg*8]);
            #pragma unroll
            for (int mt = 0; mt < 4; ++mt)
                acc[mt] = __builtin_amdgcn_mfma_f32_16x16x32_bf16(afr[mt][kk], bfr, acc[mt], 0, 0, 0);
        }
        float bias = vbias[n];
        if (rowblk == 0 && split == 0 && t == 0 && tile == 0)
            chk[0] = acc[0][0] + bias;
        #pragma unroll
        for (int mt = 0; mt < 4; ++mt)
            #pragma unroll
            for (int i = 0; i < 4; ++i){
                float v = acc[mt][i] + bias;
                sums[mt][i] += expf(v);
                if (n == tg[mt][i]) targ[mt][i] += v;
            }
    }

    #pragma unroll
    for (int mt = 0; mt < 4; ++mt)
        #pragma unroll
        for (int i = 0; i < 4; ++i){
            float sv = sums[mt][i], tv = targ[mt][i];
            #pragma unroll
            for (int msk = 1; msk < 16; msk <<= 1){ sv += __shfl_xor(sv, msk); tv += __shfl_xor(tv, msk); }
            if (nl == 0){ int row = mt*16 + kg*4 + i; psum_l[wave][row] = sv; ptarg_l[wave][row] = tv; }
        }
    __syncthreads();
    if (t < 64){
        float sv = psum_l[0][t] + psum_l[1][t] + psum_l[2][t] + psum_l[3][t];
        float tv = ptarg_l[0][t] + ptarg_l[1][t] + ptarg_l[2][t] + ptarg_l[3][t];
        int r = rowblk*64 + t;
        pS[(size_t)split*ROWS + r] = sv;
        pT[(size_t)split*ROWS + r] = tv;
    }

    if (rowblk == 0 && split == 0 && t == 0){
        float s = 0.f;
        for (int k = 0; k < EE; ++k){
            float a = bf2f(zsb[k]);
            float w = VB ? bf2f(vb[k]) : bf2f(f2bf_bits(vwf[k]));
            s += a * w;
        }
        s += vbias[0];
        if (fabsf(s - chk[0]) > 0.02f) bar[133] = 1;
    }
}

__global__ __launch_bounds__(256) void k_final(const float* __restrict__ pS,
                                               const float* __restrict__ pT,
                                               const int* __restrict__ bar,
                                               float* __restrict__ outp)
{
    int r = blockIdx.x * 256 + threadIdx.x;
    float s = 0.f, g = 0.f;
    #pragma unroll
    for (int i = 0; i < VSPLIT; ++i){ s += pS[(size_t)i*ROWS + r]; g += pT[(size_t)i*ROWS + r]; }
    float v = g - logf(s);
    if (bar[132] != 0) v = 4000.0f;    // pipeline timeout sentinel
    if (bar[133] != 0) v = 5000.0f;    // MFMA layout mismatch sentinel
    outp[r] = v;
}

extern "C" void kernel_launch(void* const* d_in, const int* in_sizes, int n_in,
                              void* d_out, int out_size, void* d_ws, size_t ws_size,
                              hipStream_t stream)
{
    (void)out_size;
    const float* latent   = (const float*)d_in[0];
    const float* trans_w  = (const float*)d_in[1];
    const float* trans_b  = (const float*)d_in[2];
    const float* anchor_w = (const float*)d_in[3];
    const float* anchor_b = (const float*)d_in[4];
    const float* vocab_w  = (const float*)d_in[5];
    const float* vocab_b  = (const float*)d_in[6];
    const int*   zi       = (const int*)d_in[7];
    const int*   y        = (const int*)d_in[8];

    float* outp = (float*)d_out;

    if (ws_size < (size_t)WS_REQ){ k_sentinel<<<16, 256, 0, stream>>>(outp, 2000.0f); return; }
    {
        bool ok = (n_in >= 9)
               && in_sizes[0] == 67108864 && in_sizes[1] == 1048576
               && in_sizes[2] == 4096     && in_sizes[3] == 4096
               && in_sizes[4] == 16       && in_sizes[5] == 8192000
               && in_sizes[6] == 32000
               && (in_sizes[7] == 32   || in_sizes[7] == 64)
               && (in_sizes[8] == 4096 || in_sizes[8] == 8192);
        if (!ok){ k_sentinel<<<16, 256, 0, stream>>>(outp, 2100.0f); return; }
    }

    char* ws = (char*)d_ws;
    unsigned short* zsb = (unsigned short*)(ws + OFF_ZSB);
    float*    pS  = (float*)(ws + OFF_PS);
    float*    pT  = (float*)(ws + OFF_PT);
    unsigned* ZNB = (unsigned*)(ws + OFF_ZNB);
    int*      bar = (int*)(ws + OFF_BAR);
    float*    PD  = (float*)(ws + OFF_PD);
    unsigned short* vbu = (unsigned short*)(ws + OFF_VB);

    const bool use_vb = ws_size >= (size_t)OFF_VB + (size_t)VB_BYTES;

    k_prep<<<1, 256, 0, stream>>>(zi, bar);
    if (use_vb)
        k_cvt<<<GG*EE/1024, 256, 0, stream>>>(vocab_w, vbu);

    k_rnn<<<NWGR, 512, 0, stream>>>(latent, zi, anchor_w, anchor_b,
                                    trans_w, trans_b, zsb, ZNB, PD, bar);

    if (use_vb)
        k_vocab<true><<<dim3(64, VSPLIT), 256, 0, stream>>>(vbu, nullptr, vocab_b,
                                                            zsb, y, pS, pT, bar);
    else
        k_vocab<false><<<dim3(64, VSPLIT), 256, 0, stream>>>(nullptr, vocab_w, vocab_b,
                                                             zsb, y, pS, pT, bar);

    k_final<<<16, 256, 0, stream>>>(pS, pT, bar, outp);
}

// Round 16
// 1768.832 us; speedup vs baseline: 1.4006x; 1.4006x over previous
//
#include <hip/hip_runtime.h>

#define EE 256
#define GG 32000
#define NSTEP 128
#define ROWS 4096
#define VSPLIT 4
#define NWGP 32
#define NWGD 64
#define NWGR (NWGP + NWGD)

typedef __attribute__((ext_vector_type(8))) short bf16x8;
typedef __attribute__((ext_vector_type(4))) float f32x4;

// ---------- workspace layout (bytes) ----------
#define OFF_ZSB  0u                      // bf16 zs 4096x256 = 2 MB
#define OFF_PS   2097152u                // f32 4x4096 = 64 KB
#define OFF_PT   (OFF_PS + 65536u)       // 64 KB
#define OFF_ZNB  (OFF_PT + 65536u)       // u32 2 planes x 32 x 128 = 32 KB
#define OFF_BAR  (OFF_ZNB + 32768u)      // 4 KB ints
#define OFF_PD   (OFF_BAR + 4096u)       // f32 16 g x 32 b x 256 e = 512 KB
#define WS_REQ   (OFF_PD + 524288u)      // 2,789,376 B (< confirmed 4,460,544)
#define OFF_VB   WS_REQ                  // optional bf16 vocab 16,384,000 B
#define VB_BYTES 16384000u

// bar int slots: flagsA[0..31] (P1 arrive), flagsB[64..127] (D arrive),
// dead@132, mfmachk@133, is64@136

__device__ __forceinline__ float wredf(float v){
    #pragma unroll
    for (int m = 1; m < 64; m <<= 1) v += __shfl_xor(v, m);
    return v;
}
__device__ __forceinline__ unsigned short f2bf_bits(float f){
    unsigned int u = __float_as_uint(f);
    unsigned int lsb = (u >> 16) & 1u;
    u += 0x7fffu + lsb;
    return (unsigned short)(u >> 16);
}
__device__ __forceinline__ float bf2f(unsigned short u){
    return __uint_as_float(((unsigned int)u) << 16);
}
__device__ __forceinline__ float aload(const float* p){
    return __hip_atomic_load(p, __ATOMIC_RELAXED, __HIP_MEMORY_SCOPE_AGENT);
}
__device__ __forceinline__ void astore(float* p, float v){
    __hip_atomic_store(p, v, __ATOMIC_RELAXED, __HIP_MEMORY_SCOPE_AGENT);
}
__device__ __forceinline__ unsigned aloadu(const unsigned* p){
    return __hip_atomic_load(p, __ATOMIC_RELAXED, __HIP_MEMORY_SCOPE_AGENT);
}
__device__ __forceinline__ void astoreu(unsigned* p, unsigned v){
    __hip_atomic_store(p, v, __ATOMIC_RELAXED, __HIP_MEMORY_SCOPE_AGENT);
}
__device__ __forceinline__ int swz(int row, int kbyte){
    return row*512 + (kbyte ^ ((row & 7) << 4));
}
// poll one flag until >= gen (with timeout -> dead)
__device__ __forceinline__ void pollflag(int* bar, int idx, int gen){
    int spins = 0;
    while (__hip_atomic_load(&bar[idx], __ATOMIC_RELAXED, __HIP_MEMORY_SCOPE_AGENT) < gen){
        __builtin_amdgcn_s_sleep(1);
        if (++spins > 2000000){
            __hip_atomic_store(&bar[132], 1, __ATOMIC_RELAXED, __HIP_MEMORY_SCOPE_AGENT);
            break;
        }
        if ((spins & 2047) == 0 &&
            __hip_atomic_load(&bar[132], __ATOMIC_RELAXED, __HIP_MEMORY_SCOPE_AGENT) != 0)
            break;
    }
}

__global__ __launch_bounds__(256) void k_sentinel(float* __restrict__ outp, float val){
    int r = blockIdx.x * 256 + threadIdx.x;
    outp[r] = val;
}

__global__ void k_prep(const int* __restrict__ zi, int* __restrict__ bar){
    int t = threadIdx.x;
    bar[t] = 0;            // re-zeroed EVERY replay
    __syncthreads();
    if (t == 0){
        bool odd_zero = true, even_ok = true;
        for (int i = 0; i < 16; ++i){
            int lo = zi[2*i], hi = zi[2*i+1];
            if (hi != 0) odd_zero = false;
            if (lo < 0 || lo >= 8192) even_ok = false;
        }
        bar[136] = (odd_zero && even_ok) ? 1 : 0;
    }
}

// ---------------- vocab f32 -> bf16 (RNE, matches pack8f) ----------------
__global__ __launch_bounds__(256) void k_cvt(const float* __restrict__ in,
                                             unsigned short* __restrict__ outp)
{
    int i = (blockIdx.x * 256 + threadIdx.x) * 4;
    float4 v = *(const float4*)&in[i];
    ushort4 o;
    o.x = f2bf_bits(v.x); o.y = f2bf_bits(v.y);
    o.z = f2bf_bits(v.z); o.w = f2bf_bits(v.w);
    *(ushort4*)&outp[i] = o;
}

// ---------------- fused recurrence: 96 WGs, producer-consumer pipeline -------
// WGs 0..31  (P1, one per batch): gather a2-weighted PD -> z -> zn -> publish
//   ZNB -> flagA ; then OVERLAPPED tail: logits/softmax (a2 stays local)/emit.
// WGs 32..95 (D): W hi/lo A-fragments in REGISTERS (loaded once); per step:
//   wait flagsA -> stage ZNB to LDS (swizzled) -> ds_read B-frags -> MFMA ->
//   publish raw U (16B-contiguous stores) -> flagB.
__global__ __launch_bounds__(512, 1) void k_rnn(const float* __restrict__ latent,
                                                const int* __restrict__ zi,
                                                const float* __restrict__ anchor_w,
                                                const float* __restrict__ anchor_b,
                                                const float* __restrict__ trans_w,
                                                const float* __restrict__ trans_b,
                                                unsigned short* __restrict__ zsb,
                                                unsigned* __restrict__ ZNB,
                                                float* __restrict__ PD,
                                                int* __restrict__ bar)
{
    __shared__ __align__(16) unsigned char ZNbRaw[2*32*512];  // 32 KB (D)
    __shared__ float xk_l[16][260];      // (P1)
    __shared__ float xv_l[16][260];      // (P1)
    __shared__ float zl[256];
    __shared__ float a2s[16];
    __shared__ float tbl[2][32];         // (D)
    __shared__ float l1s[16], l2s[16], ab_l[16], rbuf[8];

    const int wg = blockIdx.x, t = threadIdx.x;
    const int is64 = bar[136];
    const int lane = t & 63, wv = t >> 6;
    const int kg = lane >> 4, nl = lane & 15;

    if (wg < NWGP){
        // ======================= P1 role (batch b) =======================
        const int b = wg;
        int zb = is64 ? zi[2*b] : zi[b];
        const float* base = latent + (size_t)zb * 8192;  // xk=base[0:4096]*100, xv=base[4096:]*100
        for (int i = t; i < 4096; i += 512){
            int s = i >> 8, c = i & 255;
            xk_l[s][c] = base[i];
            xv_l[s][c] = base[4096 + i];
        }
        if (t < 16) ab_l[t] = anchor_b[t];
        __syncthreads();

        float zn_r = 0.f, em_r = 0.f;
        for (int stp = 0; stp < NSTEP; ++stp){
            if (stp > 0){
                if (t < NWGD) pollflag(bar, 64 + t, stp);   // wait all D done
                __syncthreads();
                __builtin_amdgcn_sched_barrier(0);
            }
            // ---- head: z update + norm + publish zn ----
            float zv = 0.f;
            if (t < 256){
                if (stp == 0) zv = base[t];
                else {
                    float dz = 0.f;
                    #pragma unroll
                    for (int g = 0; g < 16; ++g)
                        dz += a2s[g] * aload(&PD[(g*32 + b)*256 + t]);
                    zv = zn_r + em_r + dz;
                }
                float s1 = wredf(zv), s2 = wredf(zv*zv);
                if ((t & 63) == 0){ rbuf[t>>6] = s1; rbuf[4 + (t>>6)] = s2; }
            }
            __syncthreads();
            if (t < 256){
                float tot1 = rbuf[0]+rbuf[1]+rbuf[2]+rbuf[3];
                float tot2 = rbuf[4]+rbuf[5]+rbuf[6]+rbuf[7];
                float mean = tot1 * (1.0f/EE);
                float var  = (tot2 - (float)EE*mean*mean) * (1.0f/(EE-1));
                var = fmaxf(var, 0.f);
                float sc = 0.113f / (1e-5f + sqrtf(var));
                zn_r = zv * sc;
                zl[t] = zn_r;
                if (stp < NSTEP-1){
                    unsigned short zh  = f2bf_bits(zn_r);
                    unsigned short zlo = f2bf_bits(zn_r - bf2f(zh));
                    unsigned ohi = (unsigned)__shfl_xor((int)(unsigned)zh, 1);
                    unsigned olo = (unsigned)__shfl_xor((int)(unsigned)zlo, 1);
                    if (!(t & 1)){
                        astoreu(&ZNB[b*128 + (t >> 1)],        (unsigned)zh  | (ohi << 16));
                        astoreu(&ZNB[4096 + b*128 + (t >> 1)], (unsigned)zlo | (olo << 16));
                    }
                }
            }
            __syncthreads();                     // drains ZNB stores (vmcnt)
            if (stp < NSTEP-1 && t == 0)
                __hip_atomic_store(&bar[b], stp + 1, __ATOMIC_RELAXED, __HIP_MEMORY_SCOPE_AGENT);

            // ---- tail (overlaps with D phase): logits/softmax/emit ----
            if (t < 256){
                int sidx = t >> 4, L = t & 15;
                const float* aws = anchor_w + sidx*EE;
                float p1 = 0.f, p2 = 0.f;
                #pragma unroll
                for (int c = 0; c < 16; ++c){
                    int k = L*16 + c;
                    float z = zl[k];
                    p1 += z * xk_l[sidx][k];
                    p2 += z * aws[k];
                }
                #pragma unroll
                for (int mm = 1; mm < 16; mm <<= 1){ p1 += __shfl_xor(p1, mm); p2 += __shfl_xor(p2, mm); }
                if (L == 0){ l1s[sidx] = p1 * 100.0f; l2s[sidx] = p2 + ab_l[sidx]; }
            }
            __syncthreads();
            if (t < 256){
                float mx1 = -1e30f, mx2 = -1e30f;
                #pragma unroll
                for (int s = 0; s < 16; ++s){ mx1 = fmaxf(mx1, l1s[s]); mx2 = fmaxf(mx2, l2s[s]); }
                float att[16]; float sum1 = 0.f, sum2 = 0.f;
                #pragma unroll
                for (int s = 0; s < 16; ++s){
                    att[s] = expf(l1s[s] - mx1); sum1 += att[s];
                    sum2  += expf(l2s[s] - mx2);
                }
                float inv1 = 1.0f / sum1;
                if (t < 16) a2s[t] = expf(l2s[t] - mx2) / sum2;   // stays local!
                float em = 0.f;
                #pragma unroll
                for (int s = 0; s < 16; ++s) em += (att[s] * inv1) * xv_l[s][t];
                em *= 100.0f;
                em_r = em;
                zsb[((size_t)b*NSTEP + stp)*EE + t] = f2bf_bits(em);
            }
            __syncthreads();                     // a2s ready for next gather
        }
    } else {
        // ======================= D role =======================
        const int d = wg - NWGP;
        const int mh = d >> 3, q = d & 7;
        const int m = wv >> 2, et = (wv >> 1) & 1, bt = wv & 1;
        const int brow = bt*16 + nl;

        // A-fragments (W hi/lo) in registers for ALL steps (round-15-verified).
        // A[row = et*16+nl within (m,q) slice][k = kk*32 + kg*8 + j]
        bf16x8 Ah[8], Al[8];
        {
            const int grow = (2*mh + m)*256 + q*32 + et*16 + nl;
            const float* wp = trans_w + (size_t)grow * 256;
            #pragma unroll
            for (int kk = 0; kk < 8; ++kk){
                float4 w0 = *(const float4*)&wp[kk*32 + kg*8];
                float4 w1 = *(const float4*)&wp[kk*32 + kg*8 + 4];
                float ws[8] = {w0.x,w0.y,w0.z,w0.w,w1.x,w1.y,w1.z,w1.w};
                bf16x8 ah, al;
                #pragma unroll
                for (int j = 0; j < 8; ++j){
                    unsigned short hh = f2bf_bits(ws[j]);
                    ah[j] = (short)hh;
                    al[j] = (short)f2bf_bits(ws[j] - bf2f(hh));
                }
                Ah[kk] = ah; Al[kk] = al;
            }
        }
        if (t < 64) tbl[t >> 5][t & 31] = trans_b[(2*mh + (t >> 5))*256 + q*32 + (t & 31)];
        __syncthreads();

        for (int k = 1; k < NSTEP; ++k){
            if (t < NWGP) pollflag(bar, t, k);      // wait all P1 published ZNB(k-1)
            __syncthreads();
            __builtin_amdgcn_sched_barrier(0);

            // stage ZNB (hi/lo planes) to LDS, swizzled (round-14-verified)
            for (int i = t; i < 8192; i += 512){
                int p = i >> 12, rr = (i >> 7) & 31, dd = i & 127;
                unsigned v = aloadu(&ZNB[i]);
                *(unsigned*)&ZNbRaw[p*(32*512) + swz(rr, dd*4)] = v;
            }
            __syncthreads();
            {
                f32x4 acc = {0.f, 0.f, 0.f, 0.f};
                #pragma unroll
                for (int kk = 0; kk < 8; ++kk){
                    int kb = kk*64 + kg*16;
                    bf16x8 bh = *(const bf16x8*)&ZNbRaw[swz(brow, kb)];
                    bf16x8 bl = *(const bf16x8*)&ZNbRaw[32*512 + swz(brow, kb)];
                    acc = __builtin_amdgcn_mfma_f32_16x16x32_bf16(Ah[kk], bh, acc, 0, 0, 0);
                    acc = __builtin_amdgcn_mfma_f32_16x16x32_bf16(Ah[kk], bl, acc, 0, 0, 0);
                    acc = __builtin_amdgcn_mfma_f32_16x16x32_bf16(Al[kk], bh, acc, 0, 0, 0);
                }
                #pragma unroll
                for (int i = 0; i < 4; ++i){
                    int e_loc = et*16 + kg*4 + i;     // C/D: row=kg*4+i (e), col=nl (b)
                    float u = acc[i] + tbl[m][e_loc];
                    astore(&PD[(((mh << 1) + m)*32 + brow)*256 + q*32 + e_loc], u);
                }
            }
            __syncthreads();                          // drains PD stores
            if (t == 0)
                __hip_atomic_store(&bar[64 + d], k, __ATOMIC_RELAXED, __HIP_MEMORY_SCOPE_AGENT);
        }
    }
}

// ---------------- vocab: bf16 MFMA logits + streaming sumexp + target ----------
__device__ __forceinline__ bf16x8 pack8f(const float* __restrict__ src){
    bf16x8 r;
    #pragma unroll
    for (int j = 0; j < 8; ++j) r[j] = (short)f2bf_bits(src[j]);
    return r;
}

template<bool VB>
__global__ __launch_bounds__(256, 1) void k_vocab(const unsigned short* __restrict__ vb,
                                                  const float* __restrict__ vwf,
                                                  const float* __restrict__ vbias,
                                                  const unsigned short* __restrict__ zsb,
                                                  const int* __restrict__ y,
                                                  float* __restrict__ pS,
                                                  float* __restrict__ pT,
                                                  int* __restrict__ bar)
{
    const int rowblk = blockIdx.x;
    const int split  = blockIdx.y;
    const int t = threadIdx.x;
    const int wave = t >> 6, lane = t & 63;
    const int kg = lane >> 4, nl = lane & 15;
    const int is64 = bar[136];

    __shared__ float psum_l[4][64];
    __shared__ float ptarg_l[4][64];
    __shared__ float chk[1];

    bf16x8 afr[4][8];
    #pragma unroll
    for (int mt = 0; mt < 4; ++mt)
        #pragma unroll
        for (int kk = 0; kk < 8; ++kk)
            afr[mt][kk] = *(const bf16x8*)&zsb[(size_t)(rowblk*64 + mt*16 + nl) * EE + kk*32 + kg*8];

    int tg[4][4];
    #pragma unroll
    for (int mt = 0; mt < 4; ++mt)
        #pragma unroll
        for (int i = 0; i < 4; ++i){
            int rg = rowblk*64 + mt*16 + kg*4 + i;
            tg[mt][i] = is64 ? y[2*rg] : y[rg];
        }

    float sums[4][4]; float targ[4][4];
    #pragma unroll
    for (int mt = 0; mt < 4; ++mt)
        #pragma unroll
        for (int i = 0; i < 4; ++i){ sums[mt][i] = 0.f; targ[mt][i] = 0.f; }

    for (int tile = wave; tile < 500; tile += 4){
        int n = split*8000 + tile*16 + nl;
        f32x4 acc[4];
        #pragma unroll
        for (int mt = 0; mt < 4; ++mt) acc[mt] = (f32x4){0.f,0.f,0.f,0.f};
        #pragma unroll
        for (int kk = 0; kk < 8; ++kk){
            bf16x8 bfr;
            if (VB) bfr = *(const bf16x8*)&vb[(size_t)n * EE + kk*32 + kg*8];
            else    bfr = pack8f(&vwf[(size_t)n * EE + kk*32 + kg*8]);
            #pragma unroll
            for (int mt = 0; mt < 4; ++mt)
                acc[mt] = __builtin_amdgcn_mfma_f32_16x16x32_bf16(afr[mt][kk], bfr, acc[mt], 0, 0, 0);
        }
        float bias = vbias[n];
        if (rowblk == 0 && split == 0 && t == 0 && tile == 0)
            chk[0] = acc[0][0] + bias;
        #pragma unroll
        for (int mt = 0; mt < 4; ++mt)
            #pragma unroll
            for (int i = 0; i < 4; ++i){
                float v = acc[mt][i] + bias;
                sums[mt][i] += expf(v);
                if (n == tg[mt][i]) targ[mt][i] += v;
            }
    }

    #pragma unroll
    for (int mt = 0; mt < 4; ++mt)
        #pragma unroll
        for (int i = 0; i < 4; ++i){
            float sv = sums[mt][i], tv = targ[mt][i];
            #pragma unroll
            for (int msk = 1; msk < 16; msk <<= 1){ sv += __shfl_xor(sv, msk); tv += __shfl_xor(tv, msk); }
            if (nl == 0){ int row = mt*16 + kg*4 + i; psum_l[wave][row] = sv; ptarg_l[wave][row] = tv; }
        }
    __syncthreads();
    if (t < 64){
        float sv = psum_l[0][t] + psum_l[1][t] + psum_l[2][t] + psum_l[3][t];
        float tv = ptarg_l[0][t] + ptarg_l[1][t] + ptarg_l[2][t] + ptarg_l[3][t];
        int r = rowblk*64 + t;
        pS[(size_t)split*ROWS + r] = sv;
        pT[(size_t)split*ROWS + r] = tv;
    }

    if (rowblk == 0 && split == 0 && t == 0){
        float s = 0.f;
        for (int k = 0; k < EE; ++k){
            float a = bf2f(zsb[k]);
            float w = VB ? bf2f(vb[k]) : bf2f(f2bf_bits(vwf[k]));
            s += a * w;
        }
        s += vbias[0];
        if (fabsf(s - chk[0]) > 0.02f) bar[133] = 1;
    }
}

__global__ __launch_bounds__(256) void k_final(const float* __restrict__ pS,
                                               const float* __restrict__ pT,
                                               const int* __restrict__ bar,
                                               float* __restrict__ outp)
{
    int r = blockIdx.x * 256 + threadIdx.x;
    float s = 0.f, g = 0.f;
    #pragma unroll
    for (int i = 0; i < VSPLIT; ++i){ s += pS[(size_t)i*ROWS + r]; g += pT[(size_t)i*ROWS + r]; }
    float v = g - logf(s);
    if (bar[132] != 0) v = 4000.0f;    // pipeline timeout sentinel
    if (bar[133] != 0) v = 5000.0f;    // MFMA layout mismatch sentinel
    outp[r] = v;
}

extern "C" void kernel_launch(void* const* d_in, const int* in_sizes, int n_in,
                              void* d_out, int out_size, void* d_ws, size_t ws_size,
                              hipStream_t stream)
{
    (void)out_size;
    const float* latent   = (const float*)d_in[0];
    const float* trans_w  = (const float*)d_in[1];
    const float* trans_b  = (const float*)d_in[2];
    const float* anchor_w = (const float*)d_in[3];
    const float* anchor_b = (const float*)d_in[4];
    const float* vocab_w  = (const float*)d_in[5];
    const float* vocab_b  = (const float*)d_in[6];
    const int*   zi       = (const int*)d_in[7];
    const int*   y        = (const int*)d_in[8];

    float* outp = (float*)d_out;

    if (ws_size < (size_t)WS_REQ){ k_sentinel<<<16, 256, 0, stream>>>(outp, 2000.0f); return; }
    {
        bool ok = (n_in >= 9)
               && in_sizes[0] == 67108864 && in_sizes[1] == 1048576
               && in_sizes[2] == 4096     && in_sizes[3] == 4096
               && in_sizes[4] == 16       && in_sizes[5] == 8192000
               && in_sizes[6] == 32000
               && (in_sizes[7] == 32   || in_sizes[7] == 64)
               && (in_sizes[8] == 4096 || in_sizes[8] == 8192);
        if (!ok){ k_sentinel<<<16, 256, 0, stream>>>(outp, 2100.0f); return; }
    }

    char* ws = (char*)d_ws;
    unsigned short* zsb = (unsigned short*)(ws + OFF_ZSB);
    float*    pS  = (float*)(ws + OFF_PS);
    float*    pT  = (float*)(ws + OFF_PT);
    unsigned* ZNB = (unsigned*)(ws + OFF_ZNB);
    int*      bar = (int*)(ws + OFF_BAR);
    float*    PD  = (float*)(ws + OFF_PD);
    unsigned short* vbu = (unsigned short*)(ws + OFF_VB);

    const bool use_vb = ws_size >= (size_t)OFF_VB + (size_t)VB_BYTES;

    k_prep<<<1, 256, 0, stream>>>(zi, bar);
    if (use_vb)
        k_cvt<<<GG*EE/1024, 256, 0, stream>>>(vocab_w, vbu);

    k_rnn<<<NWGR, 512, 0, stream>>>(latent, zi, anchor_w, anchor_b,
                                    trans_w, trans_b, zsb, ZNB, PD, bar);

    if (use_vb)
        k_vocab<true><<<dim3(64, VSPLIT), 256, 0, stream>>>(vbu, nullptr, vocab_b,
                                                            zsb, y, pS, pT, bar);
    else
        k_vocab<false><<<dim3(64, VSPLIT), 256, 0, stream>>>(nullptr, vocab_w, vocab_b,
                                                             zsb, y, pS, pT, bar);

    k_final<<<16, 256, 0, stream>>>(pS, pT, bar, outp);
}